// Round 1
// 2153.250 us; speedup vs baseline: 1.0808x; 1.0808x over previous
//
#include <hip/hip_runtime.h>
#include <hip/hip_bf16.h>
#include <stdint.h>

#define EPS_GN 1e-5f
#define NEG_SLOPE 0.2f

static constexpr int  Bn   = 2;
static constexpr int  Cn   = 32;
static constexpr int  Dn   = 24;
static constexpr int  Hn   = 160;
static constexpr int  Wn   = 160;
static constexpr int  HWn  = Hn * Wn;              // 25600
static constexpr long DHWn = (long)Dn * HWn;       // 614400
static constexpr long NPIX = (long)Bn * Dn * HWn;  // 1228800

using frag8  = __attribute__((ext_vector_type(8)))  short;  // 8 bf16 (4 VGPRs)
using accf16 = __attribute__((ext_vector_type(16))) float;  // 32x32 C/D frag

__device__ __forceinline__ float bf2f(__hip_bfloat16 v) { return __bfloat162float(v); }
__device__ __forceinline__ __hip_bfloat16 f2bf(float v) { return __float2bfloat16(v); }
__device__ __forceinline__ float sigm(float v) { return 1.f / (1.f + __expf(-v)); }
__device__ __forceinline__ float tanh_(float v) {
    float e = __expf(2.f * v);
    return 1.f - 2.f / (e + 1.f);
}

// ---------------------------------------------------------------------------
// Pack conv1 weight w_f1 [64][32][3] into MFMA B-frag order.
// K-order: k = kd*32 + ci. dst[((kb*2+nt)*64+lane)*8+j]:
//   o = nt*32 + (lane&31), k = kb*16 + (lane>>5)*8 + j.
// ---------------------------------------------------------------------------
__global__ __launch_bounds__(256) void bpack1_kernel(
    const float* __restrict__ w, __hip_bfloat16* __restrict__ dst)
{
    int t = blockIdx.x * 256 + threadIdx.x;
    if (t >= 6 * 2 * 64 * 8) return;
    int j    = t & 7;
    int lane = (t >> 3) & 63;
    int idx  = t >> 9;           // kb*2+nt
    int nt   = idx & 1;
    int kb   = idx >> 1;         // 0..5
    int o    = nt * 32 + (lane & 31);
    int k    = kb * 16 + (lane >> 5) * 8 + j;
    int ci   = k & 31;
    int kd   = k >> 5;
    dst[t] = f2bf(w[(o * 32 + ci) * 3 + kd]);
}

// ---------------------------------------------------------------------------
// Pack conv2 weight w_f2 [32][64][3]. K-order: k = kd*64 + ci.
// dst[(kb*64+lane)*8+j]: o = lane&31, k = kb*16 + (lane>>5)*8 + j.
// ---------------------------------------------------------------------------
__global__ __launch_bounds__(256) void bpack2_kernel(
    const float* __restrict__ w, __hip_bfloat16* __restrict__ dst)
{
    int t = blockIdx.x * 256 + threadIdx.x;
    if (t >= 12 * 64 * 8) return;
    int j    = t & 7;
    int lane = (t >> 3) & 63;
    int kb   = t >> 9;           // 0..11
    int o    = lane & 31;
    int k    = kb * 16 + (lane >> 5) * 8 + j;
    int ci   = k & 63;
    int kd   = k >> 6;
    dst[t] = f2bf(w[(o * 64 + ci) * 3 + kd]);
}

// ---------------------------------------------------------------------------
// Pack GRU conv weight [32][64][3][3] fp32 into MFMA B-fragment lane order.
// ---------------------------------------------------------------------------
__global__ __launch_bounds__(256) void bpack_kernel(
    const float* __restrict__ w, __hip_bfloat16* __restrict__ dst)
{
    int t = blockIdx.x * 256 + threadIdx.x;
    if (t >= 9 * 4 * 64 * 8) return;
    int j    = t & 7;
    int lane = (t >> 3) & 63;
    int kb   = (t >> 9) & 3;
    int tap  = t >> 11;
    int ci   = kb * 16 + (lane >> 5) * 8 + j;
    int o    = lane & 31;
    dst[t] = f2bf(w[(o * 64 + ci) * 9 + tap]);
}

// ---------------------------------------------------------------------------
// x [B][C][D][HW] fp32 -> xhwc [B][D][HW][32] bf16 via LDS transpose tile.
// ---------------------------------------------------------------------------
__global__ __launch_bounds__(256) void tohwc_kernel(
    const float* __restrict__ x, __hip_bfloat16* __restrict__ xhwc)
{
    __shared__ float tile[32][65];
    int bd = blockIdx.y;            // b*Dn+d
    int b  = bd / Dn, d = bd % Dn;
    int p0 = blockIdx.x * 64;
    const float* xb = x + (long)b * Cn * DHWn + (long)d * HWn + p0;
    for (int e = threadIdx.x; e < 2048; e += 256) {
        int c = e >> 6, p = e & 63;
        tile[c][p] = xb[(long)c * DHWn + p];
    }
    __syncthreads();
    __hip_bfloat16* ob = xhwc + ((long)bd * HWn + p0) * 32;
    for (int e = threadIdx.x; e < 2048; e += 256) {
        int p = e >> 5, c = e & 31;
        ob[p * 32 + c] = f2bf(tile[c][p]);
    }
}

// ---------------------------------------------------------------------------
// conv1 via MFMA: M=pixels (32/tile), N=64 (2 N-tiles), K=96 (3 kd x 32 ch).
// Reads xhwc, writes pre-GN A [D][HW][64] bf16 for batch b.
// GN stats fused: per-channel sum/sumsq -> LDS -> global atomics.
// ---------------------------------------------------------------------------
__global__ __launch_bounds__(256) void conv1_mfma(
    const __hip_bfloat16* __restrict__ xhwc,
    const __hip_bfloat16* __restrict__ Bp1,
    const float* __restrict__ b1,
    int b,
    __hip_bfloat16* __restrict__ A,
    float* __restrict__ gsum, float* __restrict__ gsq)
{
    int wave = threadIdx.x >> 6;
    int lane = threadIdx.x & 63;
    int ml   = lane & 31;
    int kh   = lane >> 5;
    int tile0 = blockIdx.x * 8 + wave * 2;   // even; 800 tiles per d-slice

    frag8 bf[6][2];
#pragma unroll
    for (int kb = 0; kb < 6; kb++)
#pragma unroll
        for (int nt = 0; nt < 2; nt++)
            bf[kb][nt] = *(const frag8*)(Bp1 + ((kb * 2 + nt) * 64 + lane) * 8);

    int d  = tile0 / 800;
    int p0 = (tile0 % 800) * 32;   // both tiles in same d-slice (tile0 even)

    accf16 acc[2][2];
#pragma unroll
    for (int t = 0; t < 2; t++)
#pragma unroll
        for (int nt = 0; nt < 2; nt++)
#pragma unroll
            for (int i = 0; i < 16; i++) acc[t][nt][i] = 0.f;

    for (int kd = 0; kd < 3; kd++) {
        int dd = d + kd - 1;
        bool valid = (unsigned)dd < (unsigned)Dn;
        const __hip_bfloat16* rp = xhwc + ((long)(b * Dn + dd) * HWn) * 32;
#pragma unroll
        for (int h2 = 0; h2 < 2; h2++) {
            int kb = kd * 2 + h2;
#pragma unroll
            for (int t = 0; t < 2; t++) {
                frag8 a = {};
                if (valid)
                    a = *(const frag8*)(rp + (long)(p0 + t * 32 + ml) * 32 + h2 * 16 + kh * 8);
                acc[t][0] = __builtin_amdgcn_mfma_f32_32x32x16_bf16(a, bf[kb][0], acc[t][0], 0, 0, 0);
                acc[t][1] = __builtin_amdgcn_mfma_f32_32x32x16_bf16(a, bf[kb][1], acc[t][1], 0, 0, 0);
            }
        }
    }

    float bias[2] = { b1[ml], b1[32 + ml] };
    float s[2] = {0.f, 0.f}, q[2] = {0.f, 0.f};
    __hip_bfloat16* Ap = A + (long)d * HWn * 64;
#pragma unroll
    for (int t = 0; t < 2; t++) {
        int pb = p0 + t * 32;
#pragma unroll
        for (int nt = 0; nt < 2; nt++) {
#pragma unroll
            for (int i = 0; i < 16; i++) {
                int row = (i & 3) + 8 * (i >> 2) + 4 * kh;
                float v = acc[t][nt][i] + bias[nt];
                Ap[(long)(pb + row) * 64 + nt * 32 + ml] = f2bf(v);
                s[nt] += v;
                q[nt] += v * v;
            }
        }
    }
#pragma unroll
    for (int nt = 0; nt < 2; nt++) {
        s[nt] += __shfl_xor(s[nt], 32);
        q[nt] += __shfl_xor(q[nt], 32);
    }
    __shared__ float ss[64], sq[64];
    if (threadIdx.x < 64) { ss[threadIdx.x] = 0.f; sq[threadIdx.x] = 0.f; }
    __syncthreads();
    if (lane < 32) {
        atomicAdd(&ss[ml],      s[0]); atomicAdd(&sq[ml],      q[0]);
        atomicAdd(&ss[32 + ml], s[1]); atomicAdd(&sq[32 + ml], q[1]);
    }
    __syncthreads();
    if (threadIdx.x < 64) {
        atomicAdd(&gsum[b * 64 + threadIdx.x], ss[threadIdx.x]);
        atomicAdd(&gsq [b * 64 + threadIdx.x], sq[threadIdx.x]);
    }
}

__global__ __launch_bounds__(64) void finalize_kernel(
    const float* __restrict__ gsum, const float* __restrict__ gsq,
    const float* __restrict__ gn_g, const float* __restrict__ gn_b,
    float* __restrict__ scal, float* __restrict__ shft, int b)
{
    int ci = threadIdx.x;
    if (ci >= 64) return;
    int g = ci >> 3;
    float s = 0.f, qq = 0.f;
#pragma unroll
    for (int k = 0; k < 8; k++) {
        s  += gsum[b * 64 + g * 8 + k];
        qq += gsq [b * 64 + g * 8 + k];
    }
    float N   = 8.0f * (float)DHWn;
    float mu  = s / N;
    float var = qq / N - mu * mu;
    float rs  = rsqrtf(var + EPS_GN);
    float scv = rs * gn_g[ci];
    scal[b * 64 + ci] = scv;
    shft[b * 64 + ci] = gn_b[ci] - mu * scv;
}

// ---------------------------------------------------------------------------
// In-place GN affine + LeakyReLU on A [D][HW][64] bf16 (one batch).
// lrelu(v) = max(v, 0.2*v) for slope < 1.
// ---------------------------------------------------------------------------
__global__ __launch_bounds__(256) void act_kernel(
    __hip_bfloat16* __restrict__ A,
    const float* __restrict__ scal, const float* __restrict__ shft, int b)
{
    __shared__ float sc[64], sh[64];
    if (threadIdx.x < 64) {
        sc[threadIdx.x] = scal[b * 64 + threadIdx.x];
        sh[threadIdx.x] = shft[b * 64 + threadIdx.x];
    }
    __syncthreads();
    long i0 = ((long)blockIdx.x * 256 + threadIdx.x) * 8;
    __hip_bfloat16 loc[8];
    *(frag8*)loc = *(const frag8*)(A + i0);
    int c0 = (int)(i0 & 63);
#pragma unroll
    for (int j = 0; j < 8; j++) {
        float f  = bf2f(loc[j]);
        float an = fmaf(f, sc[c0 + j], sh[c0 + j]);
        loc[j]   = f2bf(fmaxf(an, NEG_SLOPE * an));
    }
    *(frag8*)(A + i0) = *(frag8*)loc;
}

// ---------------------------------------------------------------------------
// conv2 via MFMA: M=pixels, N=32, K=192 (3 kd x 64 ch). Reads activated A,
// adds x residual, writes out (fp32 CHW) through a padded-LDS transpose so
// stores are coalesced 128B channel rows.
// ---------------------------------------------------------------------------
__global__ __launch_bounds__(256) void conv2_mfma(
    const __hip_bfloat16* __restrict__ Aact,
    const __hip_bfloat16* __restrict__ Bp2,
    const float* __restrict__ b2,
    const float* __restrict__ x,
    float* __restrict__ out,
    int b)
{
    int wave = threadIdx.x >> 6;
    int lane = threadIdx.x & 63;
    int ml   = lane & 31;
    int kh   = lane >> 5;
    int tile0 = blockIdx.x * 8 + wave * 2;

    frag8 bf[12];
#pragma unroll
    for (int kb = 0; kb < 12; kb++)
        bf[kb] = *(const frag8*)(Bp2 + (kb * 64 + lane) * 8);

    int d  = tile0 / 800;
    int p0 = (tile0 % 800) * 32;

    accf16 acc[2];
#pragma unroll
    for (int t = 0; t < 2; t++)
#pragma unroll
        for (int i = 0; i < 16; i++) acc[t][i] = 0.f;

    for (int kd = 0; kd < 3; kd++) {
        int dd = d + kd - 1;
        bool valid = (unsigned)dd < (unsigned)Dn;
        const __hip_bfloat16* rp = Aact + (long)dd * HWn * 64;
#pragma unroll
        for (int qq = 0; qq < 4; qq++) {
            int kb = kd * 4 + qq;
#pragma unroll
            for (int t = 0; t < 2; t++) {
                frag8 a = {};
                if (valid)
                    a = *(const frag8*)(rp + (long)(p0 + t * 32 + ml) * 64 + qq * 16 + kh * 8);
                acc[t] = __builtin_amdgcn_mfma_f32_32x32x16_bf16(a, bf[kb], acc[t], 0, 0, 0);
            }
        }
    }

    __shared__ float tb[4][32][33];
    float bias = b2[ml];
    const float* xb = x   + (long)b * Cn * DHWn + (long)d * HWn;
    float*       ob = out + (long)b * Cn * DHWn + (long)d * HWn;
#pragma unroll
    for (int t = 0; t < 2; t++) {
        int pb = p0 + t * 32;
#pragma unroll
        for (int i = 0; i < 16; i++) {
            int row = (i & 3) + 8 * (i >> 2) + 4 * kh;
            tb[wave][row][ml] = acc[t][i] + bias;
        }
        // wave-private tile: same-wave DS ordering + compiler lgkmcnt waits
#pragma unroll
        for (int r2 = 0; r2 < 16; r2++) {
            int c = r2 * 2 + kh;
            float v = tb[wave][ml][c] + xb[(long)c * DHWn + pb + ml];
            ob[(long)c * DHWn + pb + ml] = v;
        }
    }
}

// ---------------------------------------------------------------------------
// GRU gates via MFMA. Block = 4 waves; wave handles 2 M-tiles of 32 pixels.
// ---------------------------------------------------------------------------
__global__ __launch_bounds__(256) void gru_gates_mfma(
    const __hip_bfloat16* __restrict__ xhwc,  // [B][D][HW][32]
    int dfwd, int dbwd,
    const __hip_bfloat16* __restrict__ hbf,   // [2][B][HW][32]
    const __hip_bfloat16* __restrict__ Bu,    // [9][4][64][8]
    const __hip_bfloat16* __restrict__ Br,
    const float* __restrict__ bu, const float* __restrict__ br,
    float* __restrict__ ufrag,                // [3200][1024]
    __hip_bfloat16* __restrict__ rhbf)        // [2][B][HW][32]
{
    int db   = blockIdx.y;          // dir*2 + b
    int dir  = db >> 1, b = db & 1;
    int d    = dir ? dbwd : dfwd;
    int wave = threadIdx.x >> 6;
    int lane = threadIdx.x & 63;
    int ml   = lane & 31;
    int kh   = lane >> 5;

    const __hip_bfloat16* xb = xhwc + ((long)b * Dn + d) * HWn * 32;
    const __hip_bfloat16* hb = hbf  + (long)db * HWn * 32;

    int tile0 = blockIdx.x * 8 + wave * 2;    // 0..798
    int tb[2]   = { tile0 * 32, tile0 * 32 + 32 };
    int py0[2]  = { tb[0] / Wn, tb[1] / Wn };
    int px0[2]  = { tb[0] % Wn, tb[1] % Wn };

    accf16 au[2], ar[2];
#pragma unroll
    for (int t = 0; t < 2; t++)
#pragma unroll
        for (int i = 0; i < 16; i++) { au[t][i] = 0.f; ar[t][i] = 0.f; }

    for (int tap = 0; tap < 9; tap++) {
        int dy = tap / 3 - 1, dx = tap % 3 - 1;
        long poff[2]; bool ok[2];
#pragma unroll
        for (int t = 0; t < 2; t++) {
            int yy = py0[t] + dy;
            int xx = px0[t] + ml + dx;
            ok[t]   = ((unsigned)yy < (unsigned)Hn) & ((unsigned)xx < (unsigned)Wn);
            poff[t] = ((long)(yy * Wn + xx)) * 32;
        }
#pragma unroll
        for (int kb = 0; kb < 4; kb++) {
            frag8 bu_f = *(const frag8*)(Bu + ((tap * 4 + kb) * 64 + lane) * 8);
            frag8 br_f = *(const frag8*)(Br + ((tap * 4 + kb) * 64 + lane) * 8);
            int ch = kb * 16 + kh * 8;
            const __hip_bfloat16* bsel = (kb < 2) ? (xb + ch) : (hb + (ch - 32));
#pragma unroll
            for (int t = 0; t < 2; t++) {
                frag8 a = {};
                if (ok[t]) a = *(const frag8*)(bsel + poff[t]);
                au[t] = __builtin_amdgcn_mfma_f32_32x32x16_bf16(a, bu_f, au[t], 0, 0, 0);
                ar[t] = __builtin_amdgcn_mfma_f32_32x32x16_bf16(a, br_f, ar[t], 0, 0, 0);
            }
        }
    }

    int ch = ml;
    float bias_u = bu[ch], bias_r = br[ch];
#pragma unroll
    for (int t = 0; t < 2; t++) {
        int pb = tb[t];
        float* uf = ufrag + ((long)db * 800 + tile0 + t) * 1024 + lane * 16;
        __hip_bfloat16* rhb = rhbf + (long)db * HWn * 32;
#pragma unroll
        for (int i = 0; i < 16; i++) {
            int row = (i & 3) + 8 * (i >> 2) + 4 * kh;
            int pix = pb + row;
            float hp = bf2f(hb[(long)pix * 32 + ch]);
            float uu = sigm(au[t][i] + bias_u);
            float rr = sigm(ar[t][i] + bias_r);
            uf[i] = uu;
            rhb[(long)pix * 32 + ch] = f2bf(rr * hp);
        }
    }
}

// ---------------------------------------------------------------------------
// GRU candidate + update via MFMA.
// ---------------------------------------------------------------------------
__global__ __launch_bounds__(256) void gru_cand_mfma(
    const __hip_bfloat16* __restrict__ xhwc,
    int dfwd, int dbwd,
    const __hip_bfloat16* __restrict__ rhbf,
    const __hip_bfloat16* __restrict__ Bo,
    const float* __restrict__ bo,
    const float* __restrict__ ufrag,
    __hip_bfloat16* __restrict__ hbf,
    float* __restrict__ out)
{
    int db   = blockIdx.y;
    int dir  = db >> 1, b = db & 1;
    int d    = dir ? dbwd : dfwd;
    int wave = threadIdx.x >> 6;
    int lane = threadIdx.x & 63;
    int ml   = lane & 31;
    int kh   = lane >> 5;

    const __hip_bfloat16* xb  = xhwc + ((long)b * Dn + d) * HWn * 32;
    const __hip_bfloat16* rhb = rhbf + (long)db * HWn * 32;
    __hip_bfloat16*       hb  = hbf  + (long)db * HWn * 32;

    int tile0 = blockIdx.x * 8 + wave * 2;
    int tb[2]   = { tile0 * 32, tile0 * 32 + 32 };
    int py0[2]  = { tb[0] / Wn, tb[1] / Wn };
    int px0[2]  = { tb[0] % Wn, tb[1] % Wn };

    accf16 ao[2];
#pragma unroll
    for (int t = 0; t < 2; t++)
#pragma unroll
        for (int i = 0; i < 16; i++) ao[t][i] = 0.f;

    for (int tap = 0; tap < 9; tap++) {
        int dy = tap / 3 - 1, dx = tap % 3 - 1;
        long poff[2]; bool ok[2];
#pragma unroll
        for (int t = 0; t < 2; t++) {
            int yy = py0[t] + dy;
            int xx = px0[t] + ml + dx;
            ok[t]   = ((unsigned)yy < (unsigned)Hn) & ((unsigned)xx < (unsigned)Wn);
            poff[t] = ((long)(yy * Wn + xx)) * 32;
        }
#pragma unroll
        for (int kb = 0; kb < 4; kb++) {
            frag8 bo_f = *(const frag8*)(Bo + ((tap * 4 + kb) * 64 + lane) * 8);
            int ch = kb * 16 + kh * 8;
            const __hip_bfloat16* bsel = (kb < 2) ? (xb + ch) : (rhb + (ch - 32));
#pragma unroll
            for (int t = 0; t < 2; t++) {
                frag8 a = {};
                if (ok[t]) a = *(const frag8*)(bsel + poff[t]);
                ao[t] = __builtin_amdgcn_mfma_f32_32x32x16_bf16(a, bo_f, ao[t], 0, 0, 0);
            }
        }
    }

    int ch = ml;
    float bias_o = bo[ch];
#pragma unroll
    for (int t = 0; t < 2; t++) {
        int pb = tb[t];
        const float* uf = ufrag + ((long)db * 800 + tile0 + t) * 1024 + lane * 16;
        float* ob = out + ((long)b * Cn + ch) * DHWn + (long)d * HWn;
#pragma unroll
        for (int i = 0; i < 16; i++) {
            int row = (i & 3) + 8 * (i >> 2) + 4 * kh;
            int pix = pb + row;
            float c  = tanh_(ao[t][i] + bias_o);
            float uu = uf[i];
            float hp = bf2f(hb[(long)pix * 32 + ch]);
            float hn = (1.f - uu) * hp + uu * c;
            hb[(long)pix * 32 + ch] = f2bf(hn);
            ob[pix] += hn;
        }
    }
}

// ---------------------------------------------------------------------------
extern "C" void kernel_launch(void* const* d_in, const int* in_sizes, int n_in,
                              void* d_out, int out_size, void* d_ws, size_t ws_size,
                              hipStream_t stream)
{
    const float* x    = (const float*)d_in[0];
    const float* w_f1 = (const float*)d_in[1];
    const float* b_f1 = (const float*)d_in[2];
    const float* gn_g = (const float*)d_in[3];
    const float* gn_b = (const float*)d_in[4];
    const float* w_f2 = (const float*)d_in[5];
    const float* b_f2 = (const float*)d_in[6];
    const float* w_u  = (const float*)d_in[7];
    const float* b_u  = (const float*)d_in[8];
    const float* w_r  = (const float*)d_in[9];
    const float* b_r  = (const float*)d_in[10];
    const float* w_o  = (const float*)d_in[11];
    const float* b_o  = (const float*)d_in[12];
    float* out = (float*)d_out;

    // ---- workspace layout ----
    char* ws = (char*)d_ws;
    __hip_bfloat16* Bp1 = (__hip_bfloat16*)ws;            // 6144 elems
    __hip_bfloat16* Bp2 = Bp1 + 6144;                     // 6144
    __hip_bfloat16* Bu  = Bp2 + 6144;                     // 18432 each
    __hip_bfloat16* Br  = Bu + 18432;
    __hip_bfloat16* Bo  = Br + 18432;
    float* gsum = (float*)(Bo + 18432);                   // 128 (per b,ch)
    float* gsq  = gsum + 128;                             // 128
    float* scal = gsq + 128;                              // 128
    float* shft = scal + 128;                             // 128
    char* big = (char*)(shft + 128);
    big = (char*)(((uintptr_t)big + 255) & ~(uintptr_t)255);

    // xhwc lives for the whole launch; Apre (per-b conv activations) shares
    // the second 78.6MB region with the GRU-phase buffers (disjoint lifetime).
    __hip_bfloat16* xhwc = (__hip_bfloat16*)big;                  // 78,643,200 B
    __hip_bfloat16* Apre = (__hip_bfloat16*)(big + 78643200L);    // 78,643,200 B
    __hip_bfloat16* hbf  = (__hip_bfloat16*)(big + 78643200L);    //  6,553,600 B
    __hip_bfloat16* rhbf = (__hip_bfloat16*)(big + 85196800L);    //  6,553,600 B
    float*          ufrag= (float*)        (big + 91750400L);     // 13,107,200 B

    size_t need = (size_t)(big - ws) + 157286400UL;
    if (ws_size < need) return;  // workspace too small

    // ---- weight transforms ----
    bpack1_kernel<<<24, 256, 0, stream>>>(w_f1, Bp1);
    bpack2_kernel<<<24, 256, 0, stream>>>(w_f2, Bp2);
    bpack_kernel<<<72, 256, 0, stream>>>(w_u, Bu);
    bpack_kernel<<<72, 256, 0, stream>>>(w_r, Br);
    bpack_kernel<<<72, 256, 0, stream>>>(w_o, Bo);
    hipMemsetAsync(gsum, 0, 256 * sizeof(float), stream);  // gsum+gsq

    // ---- HWC transpose (feeds conv1 AND the GRU phase) ----
    tohwc_kernel<<<dim3(400, Bn * Dn), 256, 0, stream>>>(x, xhwc);

    // ---- slice_flow path via MFMA, one batch at a time (Apre reused) ----
    for (int b = 0; b < Bn; b++) {
        conv1_mfma<<<2400, 256, 0, stream>>>(xhwc, Bp1, b_f1, b, Apre, gsum, gsq);
        finalize_kernel<<<1, 64, 0, stream>>>(gsum, gsq, gn_g, gn_b, scal, shft, b);
        act_kernel<<<19200, 256, 0, stream>>>(Apre, scal, shft, b);
        conv2_mfma<<<2400, 256, 0, stream>>>(Apre, Bp2, b_f2, x, out, b);
    }

    // ---- GRU phase ----
    hipMemsetAsync(hbf, 0, 6553600, stream);
    for (int s = 0; s < Dn; s++) {
        int dfwd = s, dbwd = Dn - 1 - s;
        gru_gates_mfma<<<dim3(100, 4), 256, 0, stream>>>(
            xhwc, dfwd, dbwd, hbf, Bu, Br, b_u, b_r, ufrag, rhbf);
        gru_cand_mfma<<<dim3(100, 4), 256, 0, stream>>>(
            xhwc, dfwd, dbwd, rhbf, Bo, b_o, ufrag, hbf, out);
    }
}

// Round 2
// 1996.029 us; speedup vs baseline: 1.1659x; 1.0788x over previous
//
#include <hip/hip_runtime.h>
#include <hip/hip_bf16.h>
#include <stdint.h>

#define EPS_GN 1e-5f
#define NEG_SLOPE 0.2f

static constexpr int  Bn   = 2;
static constexpr int  Cn   = 32;
static constexpr int  Dn   = 24;
static constexpr int  Hn   = 160;
static constexpr int  Wn   = 160;
static constexpr int  HWn  = Hn * Wn;              // 25600
static constexpr long DHWn = (long)Dn * HWn;       // 614400
static constexpr long NPIX = (long)Bn * Dn * HWn;  // 1228800

using frag8  = __attribute__((ext_vector_type(8)))  short;  // 8 bf16 (4 VGPRs)
using accf16 = __attribute__((ext_vector_type(16))) float;  // 32x32 C/D frag

__device__ __forceinline__ float bf2f(__hip_bfloat16 v) { return __bfloat162float(v); }
__device__ __forceinline__ __hip_bfloat16 f2bf(float v) { return __float2bfloat16(v); }
__device__ __forceinline__ float sigm(float v) { return 1.f / (1.f + __expf(-v)); }
__device__ __forceinline__ float tanh_(float v) {
    float e = __expf(2.f * v);
    return 1.f - 2.f / (e + 1.f);
}

// ---------------------------------------------------------------------------
// Pack conv1 weight w_f1 [64][32][3] into MFMA B-frag order.
// ---------------------------------------------------------------------------
__global__ __launch_bounds__(256) void bpack1_kernel(
    const float* __restrict__ w, __hip_bfloat16* __restrict__ dst)
{
    int t = blockIdx.x * 256 + threadIdx.x;
    if (t >= 6 * 2 * 64 * 8) return;
    int j    = t & 7;
    int lane = (t >> 3) & 63;
    int idx  = t >> 9;           // kb*2+nt
    int nt   = idx & 1;
    int kb   = idx >> 1;         // 0..5
    int o    = nt * 32 + (lane & 31);
    int k    = kb * 16 + (lane >> 5) * 8 + j;
    int ci   = k & 31;
    int kd   = k >> 5;
    dst[t] = f2bf(w[(o * 32 + ci) * 3 + kd]);
}

// ---------------------------------------------------------------------------
// Pack conv2 weight w_f2 [32][64][3]. K-order: k = kd*64 + ci.
// ---------------------------------------------------------------------------
__global__ __launch_bounds__(256) void bpack2_kernel(
    const float* __restrict__ w, __hip_bfloat16* __restrict__ dst)
{
    int t = blockIdx.x * 256 + threadIdx.x;
    if (t >= 12 * 64 * 8) return;
    int j    = t & 7;
    int lane = (t >> 3) & 63;
    int kb   = t >> 9;           // 0..11
    int o    = lane & 31;
    int k    = kb * 16 + (lane >> 5) * 8 + j;
    int ci   = k & 63;
    int kd   = k >> 6;
    dst[t] = f2bf(w[(o * 64 + ci) * 3 + kd]);
}

// ---------------------------------------------------------------------------
// Pack GRU conv weight [32][64][3][3] fp32 into MFMA B-fragment lane order.
// ---------------------------------------------------------------------------
__global__ __launch_bounds__(256) void bpack_kernel(
    const float* __restrict__ w, __hip_bfloat16* __restrict__ dst)
{
    int t = blockIdx.x * 256 + threadIdx.x;
    if (t >= 9 * 4 * 64 * 8) return;
    int j    = t & 7;
    int lane = (t >> 3) & 63;
    int kb   = (t >> 9) & 3;
    int tap  = t >> 11;
    int ci   = kb * 16 + (lane >> 5) * 8 + j;
    int o    = lane & 31;
    dst[t] = f2bf(w[(o * 64 + ci) * 9 + tap]);
}

// ---------------------------------------------------------------------------
// x [B][C][D][HW] fp32 -> xhwc [B][D][HW][32] bf16 via LDS transpose tile.
// ---------------------------------------------------------------------------
__global__ __launch_bounds__(256) void tohwc_kernel(
    const float* __restrict__ x, __hip_bfloat16* __restrict__ xhwc)
{
    __shared__ float tile[32][65];
    int bd = blockIdx.y;            // b*Dn+d
    int b  = bd / Dn, d = bd % Dn;
    int p0 = blockIdx.x * 64;
    const float* xb = x + (long)b * Cn * DHWn + (long)d * HWn + p0;
    for (int e = threadIdx.x; e < 2048; e += 256) {
        int c = e >> 6, p = e & 63;
        tile[c][p] = xb[(long)c * DHWn + p];
    }
    __syncthreads();
    __hip_bfloat16* ob = xhwc + ((long)bd * HWn + p0) * 32;
    for (int e = threadIdx.x; e < 2048; e += 256) {
        int p = e >> 5, c = e & 31;
        ob[p * 32 + c] = f2bf(tile[c][p]);
    }
}

// ---------------------------------------------------------------------------
// conv1 via MFMA: M=pixels (32/tile), N=64, K=96. GN stats fused.
// ---------------------------------------------------------------------------
__global__ __launch_bounds__(256) void conv1_mfma(
    const __hip_bfloat16* __restrict__ xhwc,
    const __hip_bfloat16* __restrict__ Bp1,
    const float* __restrict__ b1,
    int b,
    __hip_bfloat16* __restrict__ A,
    float* __restrict__ gsum, float* __restrict__ gsq)
{
    int wave = threadIdx.x >> 6;
    int lane = threadIdx.x & 63;
    int ml   = lane & 31;
    int kh   = lane >> 5;
    int tile0 = blockIdx.x * 8 + wave * 2;   // even; 800 tiles per d-slice

    frag8 bf[6][2];
#pragma unroll
    for (int kb = 0; kb < 6; kb++)
#pragma unroll
        for (int nt = 0; nt < 2; nt++)
            bf[kb][nt] = *(const frag8*)(Bp1 + ((kb * 2 + nt) * 64 + lane) * 8);

    int d  = tile0 / 800;
    int p0 = (tile0 % 800) * 32;

    accf16 acc[2][2];
#pragma unroll
    for (int t = 0; t < 2; t++)
#pragma unroll
        for (int nt = 0; nt < 2; nt++)
#pragma unroll
            for (int i = 0; i < 16; i++) acc[t][nt][i] = 0.f;

    for (int kd = 0; kd < 3; kd++) {
        int dd = d + kd - 1;
        bool valid = (unsigned)dd < (unsigned)Dn;
        const __hip_bfloat16* rp = xhwc + ((long)(b * Dn + dd) * HWn) * 32;
#pragma unroll
        for (int h2 = 0; h2 < 2; h2++) {
            int kb = kd * 2 + h2;
#pragma unroll
            for (int t = 0; t < 2; t++) {
                frag8 a = {};
                if (valid)
                    a = *(const frag8*)(rp + (long)(p0 + t * 32 + ml) * 32 + h2 * 16 + kh * 8);
                acc[t][0] = __builtin_amdgcn_mfma_f32_32x32x16_bf16(a, bf[kb][0], acc[t][0], 0, 0, 0);
                acc[t][1] = __builtin_amdgcn_mfma_f32_32x32x16_bf16(a, bf[kb][1], acc[t][1], 0, 0, 0);
            }
        }
    }

    float bias[2] = { b1[ml], b1[32 + ml] };
    float s[2] = {0.f, 0.f}, q[2] = {0.f, 0.f};
    __hip_bfloat16* Ap = A + (long)d * HWn * 64;
#pragma unroll
    for (int t = 0; t < 2; t++) {
        int pb = p0 + t * 32;
#pragma unroll
        for (int nt = 0; nt < 2; nt++) {
#pragma unroll
            for (int i = 0; i < 16; i++) {
                int row = (i & 3) + 8 * (i >> 2) + 4 * kh;
                float v = acc[t][nt][i] + bias[nt];
                Ap[(long)(pb + row) * 64 + nt * 32 + ml] = f2bf(v);
                s[nt] += v;
                q[nt] += v * v;
            }
        }
    }
#pragma unroll
    for (int nt = 0; nt < 2; nt++) {
        s[nt] += __shfl_xor(s[nt], 32);
        q[nt] += __shfl_xor(q[nt], 32);
    }
    __shared__ float ss[64], sq[64];
    if (threadIdx.x < 64) { ss[threadIdx.x] = 0.f; sq[threadIdx.x] = 0.f; }
    __syncthreads();
    if (lane < 32) {
        atomicAdd(&ss[ml],      s[0]); atomicAdd(&sq[ml],      q[0]);
        atomicAdd(&ss[32 + ml], s[1]); atomicAdd(&sq[32 + ml], q[1]);
    }
    __syncthreads();
    if (threadIdx.x < 64) {
        atomicAdd(&gsum[b * 64 + threadIdx.x], ss[threadIdx.x]);
        atomicAdd(&gsq [b * 64 + threadIdx.x], sq[threadIdx.x]);
    }
}

__global__ __launch_bounds__(64) void finalize_kernel(
    const float* __restrict__ gsum, const float* __restrict__ gsq,
    const float* __restrict__ gn_g, const float* __restrict__ gn_b,
    float* __restrict__ scal, float* __restrict__ shft, int b)
{
    int ci = threadIdx.x;
    if (ci >= 64) return;
    int g = ci >> 3;
    float s = 0.f, qq = 0.f;
#pragma unroll
    for (int k = 0; k < 8; k++) {
        s  += gsum[b * 64 + g * 8 + k];
        qq += gsq [b * 64 + g * 8 + k];
    }
    float N   = 8.0f * (float)DHWn;
    float mu  = s / N;
    float var = qq / N - mu * mu;
    float rs  = rsqrtf(var + EPS_GN);
    float scv = rs * gn_g[ci];
    scal[b * 64 + ci] = scv;
    shft[b * 64 + ci] = gn_b[ci] - mu * scv;
}

// ---------------------------------------------------------------------------
// In-place GN affine + LeakyReLU on A [D][HW][64] bf16 (one batch).
// ---------------------------------------------------------------------------
__global__ __launch_bounds__(256) void act_kernel(
    __hip_bfloat16* __restrict__ A,
    const float* __restrict__ scal, const float* __restrict__ shft, int b)
{
    __shared__ float sc[64], sh[64];
    if (threadIdx.x < 64) {
        sc[threadIdx.x] = scal[b * 64 + threadIdx.x];
        sh[threadIdx.x] = shft[b * 64 + threadIdx.x];
    }
    __syncthreads();
    long i0 = ((long)blockIdx.x * 256 + threadIdx.x) * 8;
    __hip_bfloat16 loc[8];
    *(frag8*)loc = *(const frag8*)(A + i0);
    int c0 = (int)(i0 & 63);
#pragma unroll
    for (int j = 0; j < 8; j++) {
        float f  = bf2f(loc[j]);
        float an = fmaf(f, sc[c0 + j], sh[c0 + j]);
        loc[j]   = f2bf(fmaxf(an, NEG_SLOPE * an));
    }
    *(frag8*)(A + i0) = *(frag8*)loc;
}

// ---------------------------------------------------------------------------
// conv2 via MFMA: M=pixels, N=32, K=192. 1 tile/wave for occupancy.
// Residual add + coalesced store via padded LDS transpose.
// ---------------------------------------------------------------------------
__global__ __launch_bounds__(256) void conv2_mfma(
    const __hip_bfloat16* __restrict__ Aact,
    const __hip_bfloat16* __restrict__ Bp2,
    const float* __restrict__ b2,
    const float* __restrict__ x,
    float* __restrict__ out,
    int b)
{
    int wave = threadIdx.x >> 6;
    int lane = threadIdx.x & 63;
    int ml   = lane & 31;
    int kh   = lane >> 5;
    int tile = blockIdx.x * 4 + wave;   // 0..19199

    frag8 bf[12];
#pragma unroll
    for (int kb = 0; kb < 12; kb++)
        bf[kb] = *(const frag8*)(Bp2 + (kb * 64 + lane) * 8);

    int d  = tile / 800;
    int p0 = (tile % 800) * 32;

    accf16 acc;
#pragma unroll
    for (int i = 0; i < 16; i++) acc[i] = 0.f;

    for (int kd = 0; kd < 3; kd++) {
        int dd = d + kd - 1;
        bool valid = (unsigned)dd < (unsigned)Dn;
        const __hip_bfloat16* rp = Aact + (long)dd * HWn * 64;
#pragma unroll
        for (int qq = 0; qq < 4; qq++) {
            frag8 a = {};
            if (valid)
                a = *(const frag8*)(rp + (long)(p0 + ml) * 64 + qq * 16 + kh * 8);
            acc = __builtin_amdgcn_mfma_f32_32x32x16_bf16(a, bf[kd * 4 + qq], acc, 0, 0, 0);
        }
    }

    __shared__ float tb[4][32][33];
    float bias = b2[ml];
    const float* xb = x   + (long)b * Cn * DHWn + (long)d * HWn;
    float*       ob = out + (long)b * Cn * DHWn + (long)d * HWn;
#pragma unroll
    for (int i = 0; i < 16; i++) {
        int row = (i & 3) + 8 * (i >> 2) + 4 * kh;
        tb[wave][row][ml] = acc[i] + bias;
    }
    // wave-private tile: same-wave DS ordering + compiler lgkmcnt waits
#pragma unroll
    for (int r2 = 0; r2 < 16; r2++) {
        int c = r2 * 2 + kh;
        float v = tb[wave][ml][c] + xb[(long)c * DHWn + p0 + ml];
        ob[(long)c * DHWn + p0 + ml] = v;
    }
}

// ---------------------------------------------------------------------------
// GRU reset gate via MFMA (r only): r = sigm(conv([x, h_old])); writes r*h.
// 1 M-tile (32 pixels) per wave. h double-buffered (read-only here).
// ---------------------------------------------------------------------------
__global__ __launch_bounds__(256) void gru_r_mfma(
    const __hip_bfloat16* __restrict__ xhwc,  // [B][D][HW][32]
    int dfwd, int dbwd,
    const __hip_bfloat16* __restrict__ hold,  // [2][B][HW][32]
    const __hip_bfloat16* __restrict__ Br,    // [9][4][64][8]
    const float* __restrict__ br,
    __hip_bfloat16* __restrict__ rhbf)        // [2][B][HW][32]
{
    int db   = blockIdx.y;          // dir*2 + b
    int dir  = db >> 1, b = db & 1;
    int d    = dir ? dbwd : dfwd;
    int wave = threadIdx.x >> 6;
    int lane = threadIdx.x & 63;
    int ml   = lane & 31;
    int kh   = lane >> 5;

    const __hip_bfloat16* xb = xhwc + ((long)b * Dn + d) * HWn * 32;
    const __hip_bfloat16* hb = hold + (long)db * HWn * 32;

    int tile = blockIdx.x * 4 + wave;   // 0..799
    int pb   = tile * 32;
    int py0  = pb / Wn, px0 = pb % Wn;

    accf16 ar;
#pragma unroll
    for (int i = 0; i < 16; i++) ar[i] = 0.f;

    for (int tap = 0; tap < 9; tap++) {
        int dy = tap / 3 - 1, dx = tap % 3 - 1;
        int yy = py0 + dy;
        int xx = px0 + ml + dx;
        bool ok  = ((unsigned)yy < (unsigned)Hn) & ((unsigned)xx < (unsigned)Wn);
        long poff = ((long)(yy * Wn + xx)) * 32;
#pragma unroll
        for (int kb = 0; kb < 4; kb++) {
            frag8 brf = *(const frag8*)(Br + ((tap * 4 + kb) * 64 + lane) * 8);
            int ch = kb * 16 + kh * 8;
            const __hip_bfloat16* bsel = (kb < 2) ? (xb + ch) : (hb + (ch - 32));
            frag8 a = {};
            if (ok) a = *(const frag8*)(bsel + poff);
            ar = __builtin_amdgcn_mfma_f32_32x32x16_bf16(a, brf, ar, 0, 0, 0);
        }
    }

    float bias_r = br[ml];
    __hip_bfloat16* rhb = rhbf + (long)db * HWn * 32;
#pragma unroll
    for (int i = 0; i < 16; i++) {
        int row = (i & 3) + 8 * (i >> 2) + 4 * kh;
        int pix = pb + row;
        float hp = bf2f(hb[(long)pix * 32 + ml]);
        float rr = sigm(ar[i] + bias_r);
        rhb[(long)pix * 32 + ml] = f2bf(rr * hp);
    }
}

// ---------------------------------------------------------------------------
// GRU update+candidate via MFMA: u = sigm(conv([x, h_old])),
// c = tanh(conv([x, r*h])), h_new = (1-u)h_old + u*c  (written to hnew),
// out += h_new through padded-LDS transpose (coalesced fp32 rows).
// ---------------------------------------------------------------------------
__global__ __launch_bounds__(256) void gru_cand_mfma(
    const __hip_bfloat16* __restrict__ xhwc,
    int dfwd, int dbwd,
    const __hip_bfloat16* __restrict__ hold,
    const __hip_bfloat16* __restrict__ rhbf,
    const __hip_bfloat16* __restrict__ Bu,
    const __hip_bfloat16* __restrict__ Bo,
    const float* __restrict__ bu, const float* __restrict__ bo,
    __hip_bfloat16* __restrict__ hnew,
    float* __restrict__ out)
{
    int db   = blockIdx.y;
    int dir  = db >> 1, b = db & 1;
    int d    = dir ? dbwd : dfwd;
    int wave = threadIdx.x >> 6;
    int lane = threadIdx.x & 63;
    int ml   = lane & 31;
    int kh   = lane >> 5;

    const __hip_bfloat16* xb  = xhwc + ((long)b * Dn + d) * HWn * 32;
    const __hip_bfloat16* hb  = hold + (long)db * HWn * 32;
    const __hip_bfloat16* rhb = rhbf + (long)db * HWn * 32;
    __hip_bfloat16*       hnb = hnew + (long)db * HWn * 32;

    int tile = blockIdx.x * 4 + wave;
    int pb   = tile * 32;
    int py0  = pb / Wn, px0 = pb % Wn;

    accf16 au, ao;
#pragma unroll
    for (int i = 0; i < 16; i++) { au[i] = 0.f; ao[i] = 0.f; }

    for (int tap = 0; tap < 9; tap++) {
        int dy = tap / 3 - 1, dx = tap % 3 - 1;
        int yy = py0 + dy;
        int xx = px0 + ml + dx;
        bool ok  = ((unsigned)yy < (unsigned)Hn) & ((unsigned)xx < (unsigned)Wn);
        long poff = ((long)(yy * Wn + xx)) * 32;
#pragma unroll
        for (int kb = 0; kb < 4; kb++) {
            frag8 buf = *(const frag8*)(Bu + ((tap * 4 + kb) * 64 + lane) * 8);
            frag8 bof = *(const frag8*)(Bo + ((tap * 4 + kb) * 64 + lane) * 8);
            int ch = kb * 16 + kh * 8;
            if (kb < 2) {
                frag8 a = {};
                if (ok) a = *(const frag8*)(xb + ch + poff);
                au = __builtin_amdgcn_mfma_f32_32x32x16_bf16(a, buf, au, 0, 0, 0);
                ao = __builtin_amdgcn_mfma_f32_32x32x16_bf16(a, bof, ao, 0, 0, 0);
            } else {
                frag8 ah = {}, arh = {};
                if (ok) {
                    ah  = *(const frag8*)(hb  + (ch - 32) + poff);
                    arh = *(const frag8*)(rhb + (ch - 32) + poff);
                }
                au = __builtin_amdgcn_mfma_f32_32x32x16_bf16(ah,  buf, au, 0, 0, 0);
                ao = __builtin_amdgcn_mfma_f32_32x32x16_bf16(arh, bof, ao, 0, 0, 0);
            }
        }
    }

    __shared__ float tb[4][32][33];
    float bias_u = bu[ml], bias_o = bo[ml];
    float* ob = out + (long)b * Cn * DHWn + (long)d * HWn;
#pragma unroll
    for (int i = 0; i < 16; i++) {
        int row = (i & 3) + 8 * (i >> 2) + 4 * kh;
        int pix = pb + row;
        float uu = sigm(au[i] + bias_u);
        float cc = tanh_(ao[i] + bias_o);
        float hp = bf2f(hb[(long)pix * 32 + ml]);
        float hn = (1.f - uu) * hp + uu * cc;
        hnb[(long)pix * 32 + ml] = f2bf(hn);
        tb[wave][row][ml] = hn;
    }
    // wave-private LDS tile; same-wave ordering is sufficient
#pragma unroll
    for (int r2 = 0; r2 < 16; r2++) {
        int c = r2 * 2 + kh;
        ob[(long)c * DHWn + pb + ml] += tb[wave][ml][c];
    }
}

// ---------------------------------------------------------------------------
extern "C" void kernel_launch(void* const* d_in, const int* in_sizes, int n_in,
                              void* d_out, int out_size, void* d_ws, size_t ws_size,
                              hipStream_t stream)
{
    const float* x    = (const float*)d_in[0];
    const float* w_f1 = (const float*)d_in[1];
    const float* b_f1 = (const float*)d_in[2];
    const float* gn_g = (const float*)d_in[3];
    const float* gn_b = (const float*)d_in[4];
    const float* w_f2 = (const float*)d_in[5];
    const float* b_f2 = (const float*)d_in[6];
    const float* w_u  = (const float*)d_in[7];
    const float* b_u  = (const float*)d_in[8];
    const float* w_r  = (const float*)d_in[9];
    const float* b_r  = (const float*)d_in[10];
    const float* w_o  = (const float*)d_in[11];
    const float* b_o  = (const float*)d_in[12];
    float* out = (float*)d_out;

    // ---- workspace layout ----
    char* ws = (char*)d_ws;
    __hip_bfloat16* Bp1 = (__hip_bfloat16*)ws;            // 6144 elems
    __hip_bfloat16* Bp2 = Bp1 + 6144;                     // 6144
    __hip_bfloat16* Bu  = Bp2 + 6144;                     // 18432 each
    __hip_bfloat16* Br  = Bu + 18432;
    __hip_bfloat16* Bo  = Br + 18432;
    float* gsum = (float*)(Bo + 18432);                   // 128
    float* gsq  = gsum + 128;                             // 128
    float* scal = gsq + 128;                              // 128
    float* shft = scal + 128;                             // 128
    char* big = (char*)(shft + 128);
    big = (char*)(((uintptr_t)big + 255) & ~(uintptr_t)255);

    // xhwc lives for the whole launch. Apre (conv phase) shares the second
    // 78.6MB region with the GRU-phase buffers (disjoint lifetimes).
    __hip_bfloat16* xhwc = (__hip_bfloat16*)big;                  // 78,643,200 B
    __hip_bfloat16* Apre = (__hip_bfloat16*)(big + 78643200L);    // 78,643,200 B
    __hip_bfloat16* hA   = (__hip_bfloat16*)(big + 78643200L);    //  6,553,600 B
    __hip_bfloat16* hB   = (__hip_bfloat16*)(big + 85196800L);    //  6,553,600 B
    __hip_bfloat16* rhbf = (__hip_bfloat16*)(big + 91750400L);    //  6,553,600 B

    size_t need = (size_t)(big - ws) + 157286400UL;
    if (ws_size < need) return;  // workspace too small

    // ---- weight transforms ----
    bpack1_kernel<<<24, 256, 0, stream>>>(w_f1, Bp1);
    bpack2_kernel<<<24, 256, 0, stream>>>(w_f2, Bp2);
    bpack_kernel<<<72, 256, 0, stream>>>(w_u, Bu);
    bpack_kernel<<<72, 256, 0, stream>>>(w_r, Br);
    bpack_kernel<<<72, 256, 0, stream>>>(w_o, Bo);
    hipMemsetAsync(gsum, 0, 256 * sizeof(float), stream);  // gsum+gsq

    // ---- HWC transpose (feeds conv1 AND the GRU phase) ----
    tohwc_kernel<<<dim3(400, Bn * Dn), 256, 0, stream>>>(x, xhwc);

    // ---- slice_flow path via MFMA, one batch at a time (Apre reused) ----
    for (int b = 0; b < Bn; b++) {
        conv1_mfma<<<2400, 256, 0, stream>>>(xhwc, Bp1, b_f1, b, Apre, gsum, gsq);
        finalize_kernel<<<1, 64, 0, stream>>>(gsum, gsq, gn_g, gn_b, scal, shft, b);
        act_kernel<<<19200, 256, 0, stream>>>(Apre, scal, shft, b);
        conv2_mfma<<<4800, 256, 0, stream>>>(Apre, Bp2, b_f2, x, out, b);
    }

    // ---- GRU phase: double-buffered h ----
    hipMemsetAsync(hA, 0, 6553600, stream);
    __hip_bfloat16* hbufs[2] = { hA, hB };
    for (int s = 0; s < Dn; s++) {
        int dfwd = s, dbwd = Dn - 1 - s;
        __hip_bfloat16* hold = hbufs[s & 1];
        __hip_bfloat16* hnew = hbufs[(s + 1) & 1];
        gru_r_mfma<<<dim3(200, 4), 256, 0, stream>>>(
            xhwc, dfwd, dbwd, hold, Br, b_r, rhbf);
        gru_cand_mfma<<<dim3(200, 4), 256, 0, stream>>>(
            xhwc, dfwd, dbwd, hold, rhbf, Bu, Bo, b_u, b_o, hnew, out);
    }
}